// Round 1
// baseline (2594.134 us; speedup 1.0000x reference)
//
#include <hip/hip_runtime.h>
#include <math.h>

// WaveNet on MI355X — round 1 baseline.
// Structure: 1 weight-pack kernel + 18 per-layer fused kernels (conv_f, conv_g,
// softsign, z=f*g, residual, mixer accumulation). h ping-pongs in d_ws with
// layout [B, T, 16] (channel-fastest, 64B per timestep -> coalesced float4 IO).
// fp32 VALU throughout (no fp32 MFMA on CDNA4). Compute floor ~108us.

constexpr int TL = 65536;   // T
constexpr int NBATCH = 4;   // B
constexpr int W16 = 16;     // width

// ---------------- weight packing ----------------
// conv_w/gate_w [18][o=16][i=16][k=3] -> packed [18][k=3][i=16][o=16]  (o fastest)
// res_w [17][o=16][i=16] -> [17][i=16][o=16]
// layer-0 weights folded with start_w: e0f[k][o] = sum_i conv_w[0][o][i][k]*start_w[i]
__global__ __launch_bounds__(256) void pack_kernel(
    const float* __restrict__ start_w,
    const float* __restrict__ conv_w,
    const float* __restrict__ gate_w,
    const float* __restrict__ res_w,
    float* __restrict__ wf, float* __restrict__ wg,
    float* __restrict__ rw, float* __restrict__ e0f, float* __restrict__ e0g)
{
    int idx = blockIdx.x * 256 + threadIdx.x;
    if (idx < 13824) {
        int li = idx / 768;
        int r  = idx % 768;
        int k  = r / 256;
        int i  = (r / 16) % 16;
        int o  = r % 16;
        int src = ((li * 16 + o) * 16 + i) * 3 + k;
        wf[idx] = conv_w[src];
        wg[idx] = gate_w[src];
    } else if (idx < 13824 + 4352) {
        int j  = idx - 13824;
        int li = j / 256;
        int r  = j % 256;
        int i  = r / 16;
        int o  = r % 16;
        rw[j] = res_w[(li * 16 + o) * 16 + i];
    } else if (idx < 13824 + 4352 + 96) {
        int j = idx - 13824 - 4352;   // [0,96): 48 for f, 48 for g
        int which = j / 48;
        int r = j % 48;
        int k = r / 16;
        int o = r % 16;
        const float* src = which ? gate_w : conv_w;
        float s = 0.f;
        #pragma unroll
        for (int i = 0; i < 16; ++i) s += src[(o * 16 + i) * 3 + k] * start_w[i];
        (which ? e0g : e0f)[k * 16 + o] = s;
    }
}

__device__ __forceinline__ float softsign_f(float v) {
    return v * __builtin_amdgcn_rcpf(1.0f + fabsf(v));
}

// ---------------- fused layer kernel ----------------
// MODE 0: first layer (input from x via folded start conv; writes h_out, skip=)
// MODE 1: middle layer (reads h_in, writes h_out, skip+=)
// MODE 2: last layer (reads h_in, no residual, out = skip + contribution)
template <int MODE>
__global__ __launch_bounds__(256) void layer_kernel(
    const float* __restrict__ x,
    const float* __restrict__ start_w,
    const float* __restrict__ h_in,
    float* __restrict__ h_out,
    const float* __restrict__ wf,   // MODE0: e0f[3][16]; else packed [3][16][16]
    const float* __restrict__ cb,
    const float* __restrict__ wg,
    const float* __restrict__ gb,
    const float* __restrict__ rw,   // packed [i][o], MODE 0/1
    const float* __restrict__ rb,
    const float* __restrict__ mx,   // mixer row slice for this layer [16]
    float* __restrict__ skip,
    float* __restrict__ out,
    int d)
{
    const int g = blockIdx.x * 256 + threadIdx.x;   // g = b*TL + t
    const int t = g & (TL - 1);

    float f[16], gg[16];
    #pragma unroll
    for (int o = 0; o < 16; ++o) { f[o] = cb[o]; gg[o] = gb[o]; }

    float hcur[16];  // h_in at tap t (for residual)

    if (MODE == 0) {
        float x2 = x[g];
        float x1 = (t >= 1) ? x[g - 1] : 0.f;
        float x0 = (t >= 2) ? x[g - 2] : 0.f;
        float xs[3] = {x0, x1, x2};
        #pragma unroll
        for (int k = 0; k < 3; ++k) {
            float v = xs[k];
            #pragma unroll
            for (int o = 0; o < 16; ++o) {
                f[o]  += wf[k * 16 + o] * v;
                gg[o] += wg[k * 16 + o] * v;
            }
        }
        #pragma unroll
        for (int o = 0; o < 16; ++o) hcur[o] = start_w[o] * x2;
    } else {
        #pragma unroll
        for (int k = 0; k < 3; ++k) {
            const int tk = t + (k - 2) * d;
            float in[16];
            if (tk >= 0) {
                const float4* p = (const float4*)(h_in + (size_t)(g + (k - 2) * d) * 16);
                float4 a0 = p[0], a1 = p[1], a2 = p[2], a3 = p[3];
                in[0]=a0.x; in[1]=a0.y; in[2]=a0.z; in[3]=a0.w;
                in[4]=a1.x; in[5]=a1.y; in[6]=a1.z; in[7]=a1.w;
                in[8]=a2.x; in[9]=a2.y; in[10]=a2.z; in[11]=a2.w;
                in[12]=a3.x; in[13]=a3.y; in[14]=a3.z; in[15]=a3.w;
            } else {
                #pragma unroll
                for (int i = 0; i < 16; ++i) in[i] = 0.f;
            }
            // (k,i) outer, o inner: 32 independent FMA chains, contiguous
            // wave-uniform weight fetches (s_load_dwordx16-friendly).
            #pragma unroll
            for (int i = 0; i < 16; ++i) {
                float v = in[i];
                #pragma unroll
                for (int o = 0; o < 16; ++o) {
                    f[o]  += wf[(k * 16 + i) * 16 + o] * v;
                    gg[o] += wg[(k * 16 + i) * 16 + o] * v;
                }
            }
            if (k == 2) {
                #pragma unroll
                for (int i = 0; i < 16; ++i) hcur[i] = in[i];
            }
        }
    }

    float z[16];
    #pragma unroll
    for (int o = 0; o < 16; ++o) z[o] = softsign_f(f[o]) * softsign_f(gg[o]);

    float s = 0.f;
    #pragma unroll
    for (int o = 0; o < 16; ++o) s += mx[o] * z[o];

    if (MODE == 0) {
        skip[g] = s;                    // ws is poisoned: first layer writes
    } else if (MODE == 1) {
        skip[g] += s;
    } else {
        out[g] = skip[g] + s;           // final output [B,1,T]
    }

    if (MODE != 2) {
        float hn[16];
        #pragma unroll
        for (int o = 0; o < 16; ++o) hn[o] = hcur[o] + rb[o];
        #pragma unroll
        for (int i = 0; i < 16; ++i) {
            float v = z[i];
            #pragma unroll
            for (int o = 0; o < 16; ++o) hn[o] += rw[i * 16 + o] * v;
        }
        float4* q = (float4*)(h_out + (size_t)g * 16);
        q[0] = make_float4(hn[0],  hn[1],  hn[2],  hn[3]);
        q[1] = make_float4(hn[4],  hn[5],  hn[6],  hn[7]);
        q[2] = make_float4(hn[8],  hn[9],  hn[10], hn[11]);
        q[3] = make_float4(hn[12], hn[13], hn[14], hn[15]);
    }
}

extern "C" void kernel_launch(void* const* d_in, const int* in_sizes, int n_in,
                              void* d_out, int out_size, void* d_ws, size_t ws_size,
                              hipStream_t stream) {
    const float* x       = (const float*)d_in[0];
    const float* start_w = (const float*)d_in[1];
    const float* conv_w  = (const float*)d_in[2];
    const float* conv_b  = (const float*)d_in[3];
    const float* gate_w  = (const float*)d_in[4];
    const float* gate_b  = (const float*)d_in[5];
    const float* res_w   = (const float*)d_in[6];
    const float* res_b   = (const float*)d_in[7];
    const float* mixer_w = (const float*)d_in[8];
    float* out = (float*)d_out;

    // ws layout (floats):
    float* ws  = (float*)d_ws;
    float* wf  = ws;                 // 13824  packed conv weights
    float* wg  = wf + 13824;         // 13824  packed gate weights
    float* rw  = wg + 13824;         // 4352   packed res weights
    float* e0f = rw + 4352;          // 48     layer0 folded conv weights
    float* e0g = e0f + 48;           // 48
    float* hA  = e0g + 48;           // 4194304  h ping
    float* hB  = hA + 4194304;       // 4194304  h pong
    float* skip = hB + 4194304;      // 262144   running mixer accumulation
    (void)ws_size; (void)in_sizes; (void)n_in; (void)out_size;

    pack_kernel<<<72, 256, 0, stream>>>(start_w, conv_w, gate_w, res_w,
                                        wf, wg, rw, e0f, e0g);

    static const int dil[18] = {1,2,4,8,16,32,64,128,256,1,2,4,8,16,32,64,128,256};
    const int nblk = (NBATCH * TL) / 256;   // 1024 blocks

    // layer 0 (fused start conv)
    layer_kernel<0><<<nblk, 256, 0, stream>>>(
        x, start_w, nullptr, hA,
        e0f, conv_b, e0g, gate_b,
        rw, res_b, mixer_w, skip, nullptr, 1);

    float* bufs[2] = {hA, hB};
    for (int li = 1; li < 17; ++li) {
        layer_kernel<1><<<nblk, 256, 0, stream>>>(
            nullptr, nullptr, bufs[(li - 1) & 1], bufs[li & 1],
            wf + li * 768, conv_b + li * 16, wg + li * 768, gate_b + li * 16,
            rw + li * 256, res_b + li * 16, mixer_w + li * 16,
            skip, nullptr, dil[li]);
    }

    // layer 17: no residual, writes final out = skip + contribution
    layer_kernel<2><<<nblk, 256, 0, stream>>>(
        nullptr, nullptr, bufs[0], nullptr,
        wf + 17 * 768, conv_b + 17 * 16, wg + 17 * 768, gate_b + 17 * 16,
        nullptr, nullptr, mixer_w + 17 * 16,
        skip, out, dil[17]);
}

// Round 2
// 550.065 us; speedup vs baseline: 4.7160x; 4.7160x over previous
//
#include <hip/hip_runtime.h>
#include <math.h>

// WaveNet on MI355X — round 2.
// Round-1 forensics: VGPR_Count=64 (compiler's default occupancy heuristic)
// with 64 floats of live state -> rematerialization storm (~18 junk VALU per
// useful FMA, VALUBusy 77% but 4% of fp32 peak). Fix: __launch_bounds__(256,4)
// -> 128-VGPR cap, prefetch all 3 taps into registers up front, keep the
// conv body a pure FMA stream with SGPR-resident (s_load) weights.

constexpr int TL = 65536;   // T
constexpr int NBATCH = 4;   // B

// ---------------- weight packing ----------------
// conv_w/gate_w [18][o=16][i=16][k=3] -> packed [18][k=3][i=16][o=16]  (o fastest)
// res_w [17][o=16][i=16] -> [17][i=16][o=16]
// layer-0 weights folded with start_w: e0f[k][o] = sum_i conv_w[0][o][i][k]*start_w[i]
__global__ __launch_bounds__(256) void pack_kernel(
    const float* __restrict__ start_w,
    const float* __restrict__ conv_w,
    const float* __restrict__ gate_w,
    const float* __restrict__ res_w,
    float* __restrict__ wf, float* __restrict__ wg,
    float* __restrict__ rw, float* __restrict__ e0f, float* __restrict__ e0g)
{
    int idx = blockIdx.x * 256 + threadIdx.x;
    if (idx < 13824) {
        int li = idx / 768;
        int r  = idx % 768;
        int k  = r / 256;
        int i  = (r / 16) % 16;
        int o  = r % 16;
        int src = ((li * 16 + o) * 16 + i) * 3 + k;
        wf[idx] = conv_w[src];
        wg[idx] = gate_w[src];
    } else if (idx < 13824 + 4352) {
        int j  = idx - 13824;
        int li = j / 256;
        int r  = j % 256;
        int i  = r / 16;
        int o  = r % 16;
        rw[j] = res_w[(li * 16 + o) * 16 + i];
    } else if (idx < 13824 + 4352 + 96) {
        int j = idx - 13824 - 4352;   // [0,96): 48 for f, 48 for g
        int which = j / 48;
        int r = j % 48;
        int k = r / 16;
        int o = r % 16;
        const float* src = which ? gate_w : conv_w;
        float s = 0.f;
        #pragma unroll
        for (int i = 0; i < 16; ++i) s += src[(o * 16 + i) * 3 + k] * start_w[i];
        (which ? e0g : e0f)[k * 16 + o] = s;
    }
}

__device__ __forceinline__ float softsign_f(float v) {
    return v * __builtin_amdgcn_rcpf(1.0f + fabsf(v));
}

// ---------------- fused layer kernel ----------------
// MODE 0: first layer (input from x via folded start conv; writes h_out, skip=)
// MODE 1: middle layer (reads h_in, writes h_out, skip+=)
// MODE 2: last layer (reads h_in, no residual, out = skip + contribution)
template <int MODE>
__global__ __launch_bounds__(256, 4) void layer_kernel(
    const float* __restrict__ x,
    const float* __restrict__ start_w,
    const float* __restrict__ h_in,
    float* __restrict__ h_out,
    const float* __restrict__ wf,   // MODE0: e0f[3][16]; else packed [3][16][16]
    const float* __restrict__ cb,
    const float* __restrict__ wg,
    const float* __restrict__ gb,
    const float* __restrict__ rw,   // packed [i][o], MODE 0/1
    const float* __restrict__ rb,
    const float* __restrict__ mx,   // mixer row slice for this layer [16]
    float* __restrict__ skip,
    float* __restrict__ out,
    int d)
{
    const int g = blockIdx.x * 256 + threadIdx.x;   // g = b*TL + t
    const int t = g & (TL - 1);

    float f[16], gg[16];
    #pragma unroll
    for (int o = 0; o < 16; ++o) { f[o] = cb[o]; gg[o] = gb[o]; }

    if (MODE == 0) {
        float x2 = x[g];
        float x1 = (t >= 1) ? x[g - 1] : 0.f;
        float x0 = (t >= 2) ? x[g - 2] : 0.f;
        float xs[3] = {x0, x1, x2};
        #pragma unroll
        for (int k = 0; k < 3; ++k) {
            float v = xs[k];
            #pragma unroll
            for (int o = 0; o < 16; ++o) {
                f[o]  += wf[k * 16 + o] * v;
                gg[o] += wg[k * 16 + o] * v;
            }
        }
        float z[16];
        #pragma unroll
        for (int o = 0; o < 16; ++o) z[o] = softsign_f(f[o]) * softsign_f(gg[o]);
        float s = 0.f;
        #pragma unroll
        for (int o = 0; o < 16; ++o) s += mx[o] * z[o];
        skip[g] = s;
        float hn[16];
        #pragma unroll
        for (int o = 0; o < 16; ++o) hn[o] = start_w[o] * x2 + rb[o];
        #pragma unroll
        for (int i = 0; i < 16; ++i) {
            float v = z[i];
            #pragma unroll
            for (int o = 0; o < 16; ++o) hn[o] += rw[i * 16 + o] * v;
        }
        float4* q = (float4*)(h_out + (size_t)g * 16);
        q[0] = make_float4(hn[0],  hn[1],  hn[2],  hn[3]);
        q[1] = make_float4(hn[4],  hn[5],  hn[6],  hn[7]);
        q[2] = make_float4(hn[8],  hn[9],  hn[10], hn[11]);
        q[3] = make_float4(hn[12], hn[13], hn[14], hn[15]);
        return;
    }

    // ---- prefetch all 3 taps into registers (48 floats) ----
    float in_[3][16];
    #pragma unroll
    for (int k = 0; k < 3; ++k) {
        const int off = (k - 2) * d;
        if (t + off >= 0) {
            const float4* p = (const float4*)(h_in + (size_t)(g + off) * 16);
            float4 a0 = p[0], a1 = p[1], a2 = p[2], a3 = p[3];
            in_[k][0]=a0.x;  in_[k][1]=a0.y;  in_[k][2]=a0.z;  in_[k][3]=a0.w;
            in_[k][4]=a1.x;  in_[k][5]=a1.y;  in_[k][6]=a1.z;  in_[k][7]=a1.w;
            in_[k][8]=a2.x;  in_[k][9]=a2.y;  in_[k][10]=a2.z; in_[k][11]=a2.w;
            in_[k][12]=a3.x; in_[k][13]=a3.y; in_[k][14]=a3.z; in_[k][15]=a3.w;
        } else {
            #pragma unroll
            for (int i = 0; i < 16; ++i) in_[k][i] = 0.f;
        }
    }

    // ---- conv: pure FMA stream, weights via uniform (s_load) fetches ----
    #pragma unroll
    for (int k = 0; k < 3; ++k) {
        #pragma unroll
        for (int i = 0; i < 16; ++i) {
            const float v = in_[k][i];
            const float* __restrict__ pw = wf + (k * 16 + i) * 16;
            const float* __restrict__ pg = wg + (k * 16 + i) * 16;
            #pragma unroll
            for (int o = 0; o < 16; ++o) {
                f[o]  += pw[o] * v;
                gg[o] += pg[o] * v;
            }
        }
    }

    float z[16];
    #pragma unroll
    for (int o = 0; o < 16; ++o) z[o] = softsign_f(f[o]) * softsign_f(gg[o]);

    float s = 0.f;
    #pragma unroll
    for (int o = 0; o < 16; ++o) s += mx[o] * z[o];

    if (MODE == 1) {
        skip[g] += s;
    } else {
        out[g] = skip[g] + s;           // final output [B,1,T]
    }

    if (MODE == 1) {
        float hn[16];
        #pragma unroll
        for (int o = 0; o < 16; ++o) hn[o] = in_[2][o] + rb[o];
        #pragma unroll
        for (int i = 0; i < 16; ++i) {
            float v = z[i];
            #pragma unroll
            for (int o = 0; o < 16; ++o) hn[o] += rw[i * 16 + o] * v;
        }
        float4* q = (float4*)(h_out + (size_t)g * 16);
        q[0] = make_float4(hn[0],  hn[1],  hn[2],  hn[3]);
        q[1] = make_float4(hn[4],  hn[5],  hn[6],  hn[7]);
        q[2] = make_float4(hn[8],  hn[9],  hn[10], hn[11]);
        q[3] = make_float4(hn[12], hn[13], hn[14], hn[15]);
    }
}

extern "C" void kernel_launch(void* const* d_in, const int* in_sizes, int n_in,
                              void* d_out, int out_size, void* d_ws, size_t ws_size,
                              hipStream_t stream) {
    const float* x       = (const float*)d_in[0];
    const float* start_w = (const float*)d_in[1];
    const float* conv_w  = (const float*)d_in[2];
    const float* conv_b  = (const float*)d_in[3];
    const float* gate_w  = (const float*)d_in[4];
    const float* gate_b  = (const float*)d_in[5];
    const float* res_w   = (const float*)d_in[6];
    const float* res_b   = (const float*)d_in[7];
    const float* mixer_w = (const float*)d_in[8];
    float* out = (float*)d_out;

    // ws layout (floats):
    float* ws  = (float*)d_ws;
    float* wf  = ws;                 // 13824  packed conv weights
    float* wg  = wf + 13824;         // 13824  packed gate weights
    float* rw  = wg + 13824;         // 4352   packed res weights
    float* e0f = rw + 4352;          // 48     layer0 folded conv weights
    float* e0g = e0f + 48;           // 48
    float* hA  = e0g + 48;           // 4194304  h ping
    float* hB  = hA + 4194304;       // 4194304  h pong
    float* skip = hB + 4194304;      // 262144   running mixer accumulation
    (void)ws_size; (void)in_sizes; (void)n_in; (void)out_size;

    pack_kernel<<<72, 256, 0, stream>>>(start_w, conv_w, gate_w, res_w,
                                        wf, wg, rw, e0f, e0g);

    static const int dil[18] = {1,2,4,8,16,32,64,128,256,1,2,4,8,16,32,64,128,256};
    const int nblk = (NBATCH * TL) / 256;   // 1024 blocks

    // layer 0 (fused start conv)
    layer_kernel<0><<<nblk, 256, 0, stream>>>(
        x, start_w, nullptr, hA,
        e0f, conv_b, e0g, gate_b,
        rw, res_b, mixer_w, skip, nullptr, 1);

    float* bufs[2] = {hA, hB};
    for (int li = 1; li < 17; ++li) {
        layer_kernel<1><<<nblk, 256, 0, stream>>>(
            nullptr, nullptr, bufs[(li - 1) & 1], bufs[li & 1],
            wf + li * 768, conv_b + li * 16, wg + li * 768, gate_b + li * 16,
            rw + li * 256, res_b + li * 16, mixer_w + li * 16,
            skip, nullptr, dil[li]);
    }

    // layer 17: no residual, writes final out = skip + contribution
    layer_kernel<2><<<nblk, 256, 0, stream>>>(
        nullptr, nullptr, bufs[0], nullptr,
        wf + 17 * 768, conv_b + 17 * 16, wg + 17 * 768, gate_b + 17 * 16,
        nullptr, nullptr, mixer_w + 17 * 16,
        skip, out, dil[17]);
}